// Round 24
// baseline (443.739 us; speedup 1.0000x reference)
//
#include <hip/hip_runtime.h>
#include <hip/hip_bf16.h>
#include <cstddef>
#include <cstdint>

// Mamba2 (2 layers). Round-24: GEMM LDS double-buffered — ONE barrier per
// K-epoch (write buf[c]; barrier; prefetch k+1; MFMA buf[c]; c^=1). LDS
// 32->64KB (2 blocks/CU), Bl joins the register rotation. Everything else
// identical to round-23 (verified, 443 us, absmax 0.070).

#define BATCH 4
#define SEQ   2048
#define DMODEL 512
#define DINNER 1024
#define DSTATE 128
#define HEADDIM 64
#define NHEADS 16
#define DCONV 4
#define CONVDIM 1280
#define DINPROJ 2320
#define NPAD_IN 2432          // 19 * 128
#define ROWS (BATCH * SEQ)    // 8192
#define NSEG 32               // chunks per sequence
#define TSEG 64               // chunk length

#define SWZ32(r, c)  ((r) * 32  + (((((c) >> 3) ^ (((r) >> 1) & 3)) << 3) | ((c) & 7)))
#define SWZ64(r, c)  ((r) * 64  + (((((c) >> 3) ^ ((r) & 7)) << 3) | ((c) & 7)))
#define SWZ128(r, c) ((r) * 128 + (((((c) >> 3) ^ ((r) & 7)) << 3) | ((c) & 7)))

typedef __attribute__((ext_vector_type(8))) short bf16x8;
typedef __attribute__((ext_vector_type(4))) float f32x4;

__device__ __forceinline__ float silu_f(float x) {
    return x * (1.0f / (1.0f + __expf(-x)));
}
__device__ __forceinline__ unsigned short f2bfu(float f) {  // RNE fp32->bf16
    unsigned u = __float_as_uint(f);
    unsigned r = u + 0x7FFFu + ((u >> 16) & 1u);
    return (unsigned short)(r >> 16);
}
__device__ __forceinline__ float bfu2f(unsigned short h) {
    return __uint_as_float(((unsigned)h) << 16);
}

// ---------------------------------------------------------------------------
// Split fp32 flat array -> hi/lo bf16. 8 elems/thread. (layer-0 x only)
// ---------------------------------------------------------------------------
__global__ __launch_bounds__(256)
void split_a_kernel(const float* __restrict__ A,
                    unsigned short* __restrict__ Ah,
                    unsigned short* __restrict__ Al)
{
    const size_t i = ((size_t)blockIdx.x * 256 + threadIdx.x) * 8;
    const float4 a = *(const float4*)&A[i];
    const float4 b = *(const float4*)&A[i + 4];
    float v[8] = {a.x, a.y, a.z, a.w, b.x, b.y, b.z, b.w};
    unsigned hv[8], lv[8];
#pragma unroll
    for (int j = 0; j < 8; ++j) {
        hv[j] = f2bfu(v[j]);
        lv[j] = f2bfu(v[j] - bfu2f((unsigned short)hv[j]));
    }
    uint4 ph = make_uint4(hv[0] | (hv[1] << 16), hv[2] | (hv[3] << 16),
                          hv[4] | (hv[5] << 16), hv[6] | (hv[7] << 16));
    uint4 pl = make_uint4(lv[0] | (lv[1] << 16), lv[2] | (lv[3] << 16),
                          lv[4] | (lv[5] << 16), lv[6] | (lv[7] << 16));
    *(uint4*)&Ah[i] = ph;
    *(uint4*)&Al[i] = pl;
}

// ---------------------------------------------------------------------------
// Transpose + split weight W[K][N] fp32 -> Oh/Ol[Npad][K] bf16 (n >= N -> 0).
// ---------------------------------------------------------------------------
__global__ __launch_bounds__(256)
void tsplit_w_kernel(const float* __restrict__ W, int K, int N,
                     unsigned short* __restrict__ Oh,
                     unsigned short* __restrict__ Ol)
{
    __shared__ float tile[32][33];
    const int n0 = blockIdx.x * 32, k0 = blockIdx.y * 32;
    const int c = threadIdx.x & 31, r8 = threadIdx.x >> 5;
    const int n = n0 + c;
#pragma unroll
    for (int i = 0; i < 4; ++i) {
        const int k = r8 + i * 8;
        float v = 0.0f;
        if (n < N) v = W[(size_t)(k0 + k) * N + n];
        tile[c][k] = v;
    }
    __syncthreads();
#pragma unroll
    for (int i = 0; i < 4; ++i) {
        const int nl = r8 + i * 8;
        const float v = tile[nl][c];
        const unsigned short h = f2bfu(v);
        const unsigned short l = f2bfu(v - bfu2f(h));
        const size_t o = (size_t)(n0 + nl) * K + k0 + c;
        Oh[o] = h;
        Ol[o] = l;
    }
}

// ---------------------------------------------------------------------------
// Transpose bf16 B planes: per (chunk, plane), [64 t][128 n] -> [128 n][64 t].
// ---------------------------------------------------------------------------
__global__ __launch_bounds__(256)
void tsplit_bf16_kernel(const unsigned short* __restrict__ S0,
                        const unsigned short* __restrict__ S1,
                        unsigned short* __restrict__ O0,
                        unsigned short* __restrict__ O1)
{
    __shared__ unsigned short tile[64][136];
    const int z = blockIdx.x;
    const int chunk = z >> 1, plane = z & 1;
    const unsigned short* S = plane ? S1 : S0;
    unsigned short* O = plane ? O1 : O0;
    const size_t base = (size_t)chunk * TSEG * DSTATE;
    const int tid = threadIdx.x;

#pragma unroll
    for (int i = 0; i < 4; ++i) {
        const int e8 = tid + i * 256;       // 8-ushort block 0..1023
        const int t = e8 >> 4;
        const int n = (e8 & 15) * 8;
        *(uint4*)&tile[t][n] = *(const uint4*)&S[base + (size_t)t * DSTATE + n];
    }
    __syncthreads();

    const int n = tid & 127;
    const int th = (tid >> 7) * 32;
#pragma unroll
    for (int i = 0; i < 4; ++i) {
        uint4 o;
        o.x = (unsigned)tile[th + i * 8 + 0][n] | ((unsigned)tile[th + i * 8 + 1][n] << 16);
        o.y = (unsigned)tile[th + i * 8 + 2][n] | ((unsigned)tile[th + i * 8 + 3][n] << 16);
        o.z = (unsigned)tile[th + i * 8 + 4][n] | ((unsigned)tile[th + i * 8 + 5][n] << 16);
        o.w = (unsigned)tile[th + i * 8 + 6][n] | ((unsigned)tile[th + i * 8 + 7][n] << 16);
        *(uint4*)&O[(size_t)chunk * 8192 + (size_t)n * 64 + th + i * 8] = o;
    }
}

// ---------------------------------------------------------------------------
// Split-bf16 MFMA GEMM, double-buffered LDS (1 barrier per K-epoch).
// 2-pass C = (Ah+Al)*Bh; blocks with col0+128 > exactCol0 add AhBl.
// XCD swizzle. Output modes as before.
// ---------------------------------------------------------------------------
__global__ __launch_bounds__(256)
void gemm_bf16s(const unsigned short* __restrict__ Ah,
                const unsigned short* __restrict__ Al,
                const unsigned short* __restrict__ Bh,
                const unsigned short* __restrict__ Bl,
                float* __restrict__ Cf,
                unsigned short* __restrict__ Cbh,
                int ldc, int N, int K,
                int exactCol0,
                float* __restrict__ dtf,
                unsigned short* __restrict__ Soh,
                unsigned short* __restrict__ Sol)
{
    __shared__ __align__(16) unsigned short As[2][2][128 * 32];  // [plane][buf]
    __shared__ __align__(16) unsigned short Bs[2][2][128 * 32];

    const int tid = threadIdx.x;
    const int w = tid >> 6, lane = tid & 63;
    const int wm = w >> 1, wn = w & 1;

    const int nwg = gridDim.x * gridDim.y;
    int flat = blockIdx.y * gridDim.x + blockIdx.x;
    flat = (flat & 7) * (nwg >> 3) + (flat >> 3);
    const int bx = flat % gridDim.x, by = flat / gridDim.x;
    const int row0 = by * 128, col0 = bx * 128;
    const bool exact = (col0 + 128 > exactCol0);

    const int srow = tid >> 1;
    const int sk   = (tid & 1) * 16;

    const int lr = lane & 15;
    const int lk = (lane >> 4) * 8;

    f32x4 acc[4][4];
#pragma unroll
    for (int i = 0; i < 4; ++i)
#pragma unroll
        for (int j = 0; j < 4; ++j) acc[i][j] = (f32x4){0.f, 0.f, 0.f, 0.f};

    const int sw0 = SWZ32(srow, sk);
    const int sw1 = SWZ32(srow, sk + 8);
    const size_t gabase = (size_t)(row0 + srow) * K + sk;
    const size_t gbbase = (size_t)(col0 + srow) * K + sk;

    uint4 vah0 = *(const uint4*)&Ah[gabase];
    uint4 vah1 = *(const uint4*)&Ah[gabase + 8];
    uint4 val0 = *(const uint4*)&Al[gabase];
    uint4 val1 = *(const uint4*)&Al[gabase + 8];
    uint4 vbh0 = *(const uint4*)&Bh[gbbase];
    uint4 vbh1 = *(const uint4*)&Bh[gbbase + 8];
    uint4 vbl0, vbl1;
    if (exact) {
        vbl0 = *(const uint4*)&Bl[gbbase];
        vbl1 = *(const uint4*)&Bl[gbbase + 8];
    }

    int cur = 0;
    for (int k0 = 0; k0 < K; k0 += 32) {
        // write staged regs into buf[cur] (nobody reads buf[cur] now:
        // previous epoch's readers were released by the barrier below and
        // read buf[cur^1])
        *(uint4*)&As[0][cur][sw0] = vah0;  *(uint4*)&As[0][cur][sw1] = vah1;
        *(uint4*)&As[1][cur][sw0] = val0;  *(uint4*)&As[1][cur][sw1] = val1;
        *(uint4*)&Bs[0][cur][sw0] = vbh0;  *(uint4*)&Bs[0][cur][sw1] = vbh1;
        if (exact) {
            *(uint4*)&Bs[1][cur][sw0] = vbl0;
            *(uint4*)&Bs[1][cur][sw1] = vbl1;
        }
        __syncthreads();                  // buf[cur] visible to all waves

        if (k0 + 32 < K) {                // prefetch next epoch
            const size_t ga = gabase + k0 + 32;
            const size_t gb = gbbase + k0 + 32;
            vah0 = *(const uint4*)&Ah[ga];
            vah1 = *(const uint4*)&Ah[ga + 8];
            val0 = *(const uint4*)&Al[ga];
            val1 = *(const uint4*)&Al[ga + 8];
            vbh0 = *(const uint4*)&Bh[gb];
            vbh1 = *(const uint4*)&Bh[gb + 8];
            if (exact) {
                vbl0 = *(const uint4*)&Bl[gb];
                vbl1 = *(const uint4*)&Bl[gb + 8];
            }
        }

        bf16x8 a_h[4], a_l[4], b_h[4];
#pragma unroll
        for (int mt = 0; mt < 4; ++mt) {
            const int r = wm * 64 + mt * 16 + lr;
            a_h[mt] = *(const bf16x8*)&As[0][cur][SWZ32(r, lk)];
            a_l[mt] = *(const bf16x8*)&As[1][cur][SWZ32(r, lk)];
        }
#pragma unroll
        for (int nt = 0; nt < 4; ++nt) {
            const int c = wn * 64 + nt * 16 + lr;
            b_h[nt] = *(const bf16x8*)&Bs[0][cur][SWZ32(c, lk)];
        }
#pragma unroll
        for (int mt = 0; mt < 4; ++mt)
#pragma unroll
            for (int nt = 0; nt < 4; ++nt) {
                acc[mt][nt] = __builtin_amdgcn_mfma_f32_16x16x32_bf16(a_h[mt], b_h[nt], acc[mt][nt], 0, 0, 0);
                acc[mt][nt] = __builtin_amdgcn_mfma_f32_16x16x32_bf16(a_l[mt], b_h[nt], acc[mt][nt], 0, 0, 0);
            }
        if (exact) {
            bf16x8 b_l[4];
#pragma unroll
            for (int nt = 0; nt < 4; ++nt) {
                const int c = wn * 64 + nt * 16 + lr;
                b_l[nt] = *(const bf16x8*)&Bs[1][cur][SWZ32(c, lk)];
            }
#pragma unroll
            for (int mt = 0; mt < 4; ++mt)
#pragma unroll
                for (int nt = 0; nt < 4; ++nt)
                    acc[mt][nt] = __builtin_amdgcn_mfma_f32_16x16x32_bf16(a_h[mt], b_l[nt], acc[mt][nt], 0, 0, 0);
        }
        cur ^= 1;
    }

    const int crow = (lane >> 4) * 4;
#pragma unroll
    for (int mt = 0; mt < 4; ++mt)
#pragma unroll
        for (int nt = 0; nt < 4; ++nt) {
            const int cc = col0 + wn * 64 + nt * 16 + lr;
            if (cc < N) {
#pragma unroll
                for (int r = 0; r < 4; ++r) {
                    const size_t row = (size_t)(row0 + wm * 64 + mt * 16 + crow + r);
                    const float v = acc[mt][nt][r];
                    if (Cf) {
                        const size_t oi = row * ldc + cc;
                        Cf[oi] = v;
                        if (Soh) {
                            const unsigned short h16 = f2bfu(v);
                            Soh[oi] = h16;
                            Sol[oi] = f2bfu(v - bfu2f(h16));
                        }
                    } else {
                        if (cc >= exactCol0)
                            dtf[row * NHEADS + (cc - exactCol0)] = v;
                        else
                            Cbh[row * ldc + cc] = f2bfu(v);
                    }
                }
            }
        }
}

// ---------------------------------------------------------------------------
// Depthwise causal conv (4 taps) + bias + SiLU + dt/dA precompute.
// ---------------------------------------------------------------------------
__global__ __launch_bounds__(320)
void conv_kernel(const unsigned short* __restrict__ zxh,
                 const float* __restrict__ dtraw,
                 const float* __restrict__ cw,
                 const float* __restrict__ cb,
                 const float* __restrict__ dtbias,
                 const float* __restrict__ alog,
                 float* __restrict__ xh,
                 unsigned short* __restrict__ Bsph,
                 unsigned short* __restrict__ Bspl,
                 unsigned short* __restrict__ Csph,
                 unsigned short* __restrict__ Cspl,
                 float* __restrict__ dtb,
                 float* __restrict__ dAb)
{
    const int row = blockIdx.x;
    const int l   = row & (SEQ - 1);
    const int c4  = threadIdx.x * 4;

    float4 acc = *(const float4*)&cb[c4];
#pragma unroll
    for (int k = 0; k < DCONV; ++k) {
        const int lk = l - (DCONV - 1) + k;
        if (lk >= 0) {
            const uint2 vv = *(const uint2*)&zxh[(size_t)(row - (DCONV - 1) + k) * DINPROJ + DINNER + c4];
            float4 v;
            v.x = bfu2f((unsigned short)(vv.x & 0xffff));
            v.y = bfu2f((unsigned short)(vv.x >> 16));
            v.z = bfu2f((unsigned short)(vv.y & 0xffff));
            v.w = bfu2f((unsigned short)(vv.y >> 16));
            const float4 w = *(const float4*)&cw[k * CONVDIM + c4];
            acc.x = fmaf(v.x, w.x, acc.x);
            acc.y = fmaf(v.y, w.y, acc.y);
            acc.z = fmaf(v.z, w.z, acc.z);
            acc.w = fmaf(v.w, w.w, acc.w);
        }
    }
    acc.x = silu_f(acc.x);
    acc.y = silu_f(acc.y);
    acc.z = silu_f(acc.z);
    acc.w = silu_f(acc.w);

    if (c4 < DINNER) {
        *(float4*)&xh[(size_t)row * DINNER + c4] = acc;
    } else {
        float o[4] = {acc.x, acc.y, acc.z, acc.w};
        unsigned hv[4], lv[4];
#pragma unroll
        for (int j = 0; j < 4; ++j) {
            hv[j] = f2bfu(o[j]);
            lv[j] = f2bfu(o[j] - bfu2f((unsigned short)hv[j]));
        }
        const uint2 ph = make_uint2(hv[0] | (hv[1] << 16), hv[2] | (hv[3] << 16));
        const uint2 pl = make_uint2(lv[0] | (lv[1] << 16), lv[2] | (lv[3] << 16));
        if (c4 < DINNER + DSTATE) {
            const size_t oi = (size_t)row * DSTATE + (c4 - DINNER);
            *(uint2*)&Bsph[oi] = ph;
            *(uint2*)&Bspl[oi] = pl;
        } else {
            const size_t oi = (size_t)row * DSTATE + (c4 - DINNER - DSTATE);
            *(uint2*)&Csph[oi] = ph;
            *(uint2*)&Cspl[oi] = pl;
        }
    }

    if (threadIdx.x < NHEADS) {
        const int hh = threadIdx.x;
        const float raw = dtraw[(size_t)row * NHEADS + hh] + dtbias[hh];
        const float dtv = (raw > 20.0f) ? raw : log1pf(expf(raw));
        const float a = expf(alog[hh]);
        dtb[row * NHEADS + hh] = dtv;
        dAb[row * NHEADS + hh] = expf(-a * dtv);
    }
}

// ---------------------------------------------------------------------------
// meta: per (b,h,chunk) wave: l[t] = inclusive cumsum(-a*dt); w; ptot.
// ---------------------------------------------------------------------------
__global__ __launch_bounds__(64)
void meta_kernel(const float* __restrict__ dtb,
                 const float* __restrict__ alog,
                 float* __restrict__ lB, float* __restrict__ wB,
                 float* __restrict__ ptot)
{
    const int bhc = blockIdx.x;
    const int chunk = bhc & 31;
    const int h = (bhc >> 5) & 15;
    const int b = bhc >> 9;
    const int t = threadIdx.x;
    const size_t row0 = (size_t)b * SEQ + (size_t)chunk * TSEG;

    const float a = __expf(alog[h]);
    const float dtv = dtb[(row0 + t) * NHEADS + h];
    float v = -a * dtv;
#pragma unroll
    for (int off = 1; off < 64; off <<= 1) {
        const float u = __shfl_up(v, off, 64);
        if (t >= off) v += u;
    }
    const float l63 = __shfl(v, 63, 64);
    lB[(size_t)bhc * 64 + t] = v;
    wB[(size_t)bhc * 64 + t] = __expf(l63 - v) * dtv;
    if (t == 0) ptot[bhc] = __expf(l63);
}

// ---------------------------------------------------------------------------
// cb: CB[t][s] = C_chunk @ B_chunk^T per (b,chunk). Swizzled (SWZ128).
// ---------------------------------------------------------------------------
__global__ __launch_bounds__(256)
void cb_kernel(const unsigned short* __restrict__ Ch,
               const unsigned short* __restrict__ Cl,
               const unsigned short* __restrict__ Bh_,
               const unsigned short* __restrict__ Bl_,
               float* __restrict__ CBo)
{
    __shared__ __align__(16) unsigned short Cs[2][64 * 128];
    __shared__ __align__(16) unsigned short Bs2[2][64 * 128];
    const int bc = blockIdx.x;
    const size_t base = (size_t)bc * 8192;
    const int tid = threadIdx.x;
#pragma unroll
    for (int i = 0; i < 4; ++i) {
        const int bi = tid + i * 256;           // 16B block 0..1023
        const int r = bi >> 4, c = (bi & 15) << 3;
        const int d = SWZ128(r, c);
        *(uint4*)&Cs[0][d]  = ((const uint4*)(Ch  + base))[bi];
        *(uint4*)&Cs[1][d]  = ((const uint4*)(Cl  + base))[bi];
        *(uint4*)&Bs2[0][d] = ((const uint4*)(Bh_ + base))[bi];
        *(uint4*)&Bs2[1][d] = ((const uint4*)(Bl_ + base))[bi];
    }
    __syncthreads();

    const int w = tid >> 6, lane = tid & 63;
    const int lr = lane & 15, lk = (lane >> 4) * 8;
    f32x4 acc[4];
#pragma unroll
    for (int i = 0; i < 4; ++i) acc[i] = (f32x4){0.f, 0.f, 0.f, 0.f};

#pragma unroll
    for (int kk = 0; kk < 4; ++kk) {
        const int k0 = kk * 32;
        const int ar = w * 16 + lr;
        const bf16x8 ah = *(const bf16x8*)&Cs[0][SWZ128(ar, k0 + lk)];
        const bf16x8 al = *(const bf16x8*)&Cs[1][SWZ128(ar, k0 + lk)];
#pragma unroll
        for (int st = 0; st < 4; ++st) {
            const int br = st * 16 + lr;
            const bf16x8 bh = *(const bf16x8*)&Bs2[0][SWZ128(br, k0 + lk)];
            const bf16x8 bl = *(const bf16x8*)&Bs2[1][SWZ128(br, k0 + lk)];
            acc[st] = __builtin_amdgcn_mfma_f32_16x16x32_bf16(ah, bh, acc[st], 0, 0, 0);
            acc[st] = __builtin_amdgcn_mfma_f32_16x16x32_bf16(ah, bl, acc[st], 0, 0, 0);
            acc[st] = __builtin_amdgcn_mfma_f32_16x16x32_bf16(al, bh, acc[st], 0, 0, 0);
        }
    }
    const int crow = (lane >> 4) * 4;
#pragma unroll
    for (int st = 0; st < 4; ++st)
#pragma unroll
        for (int r = 0; r < 4; ++r)
            CBo[(size_t)bc * 4096 + (size_t)(w * 16 + crow + r) * 64 + st * 16 + lr] = acc[st][r];
}

// ---------------------------------------------------------------------------
// state: S[n][p] = sum_t (B[t,n]*w[t]) * x[t,p] per (b,h,chunk). Swizzled.
// Writes bf16 states.
// ---------------------------------------------------------------------------
__global__ __launch_bounds__(256)
void state_kernel(const unsigned short* __restrict__ BTh,
                  const unsigned short* __restrict__ BTl,
                  const float* __restrict__ xh,
                  const float* __restrict__ wB,
                  unsigned short* __restrict__ hloc)
{
    __shared__ __align__(16) unsigned short BTs[2][128 * 64];
    __shared__ __align__(16) unsigned short xwT[2][64 * 64];

    const int bhc = blockIdx.x;
    const int chunk = bhc & 31;
    const int h = (bhc >> 5) & 15;
    const int b = bhc >> 9;
    const int bc = b * 32 + chunk;
    const size_t row0 = (size_t)b * SEQ + (size_t)chunk * TSEG;
    const int tid = threadIdx.x;

    const size_t bbase = (size_t)bc * 8192;
#pragma unroll
    for (int i = 0; i < 4; ++i) {
        const int bi = tid + i * 256;           // 16B block 0..1023
        const int r = bi >> 3, c = (bi & 7) << 3;
        const int d = SWZ64(r, c);
        *(uint4*)&BTs[0][d] = ((const uint4*)(BTh + bbase))[bi];
        *(uint4*)&BTs[1][d] = ((const uint4*)(BTl + bbase))[bi];
    }
    {
        const int t = tid & 63;
        const int pb = (tid >> 6) * 16;
        const float wv = wB[(size_t)bhc * 64 + t];
        const float* xr = &xh[(row0 + t) * DINNER + h * HEADDIM + pb];
#pragma unroll
        for (int i = 0; i < 16; ++i) {
            const int p = pb + i;
            const float v = xr[i] * wv;
            const unsigned short hh = f2bfu(v);
            const int d = SWZ64(p, t);
            xwT[0][d] = hh;
            xwT[1][d] = f2bfu(v - bfu2f(hh));
        }
    }
    __syncthreads();

    const int w = tid >> 6, lane = tid & 63;
    const int lr = lane & 15, lk = (lane >> 4) * 8;
    f32x4 acc[2][4];
#pragma unroll
    for (int i = 0; i < 2; ++i)
#pragma unroll
        for (int j = 0; j < 4; ++j) acc[i][j] = (f32x4){0.f, 0.f, 0.f, 0.f};

#pragma unroll
    for (int kk = 0; kk < 2; ++kk) {
        const int k0 = kk * 32;
        bf16x8 ah[2], al[2];
#pragma unroll
        for (int nt = 0; nt < 2; ++nt) {
            const int n = w * 32 + nt * 16 + lr;
            ah[nt] = *(const bf16x8*)&BTs[0][SWZ64(n, k0 + lk)];
            al[nt] = *(const bf16x8*)&BTs[1][SWZ64(n, k0 + lk)];
        }
#pragma unroll
        for (int pt = 0; pt < 4; ++pt) {
            const int pr = pt * 16 + lr;
            const bf16x8 bh = *(const bf16x8*)&xwT[0][SWZ64(pr, k0 + lk)];
            const bf16x8 bl = *(const bf16x8*)&xwT[1][SWZ64(pr, k0 + lk)];
#pragma unroll
            for (int nt = 0; nt < 2; ++nt) {
                acc[nt][pt] = __builtin_amdgcn_mfma_f32_16x16x32_bf16(ah[nt], bh, acc[nt][pt], 0, 0, 0);
                acc[nt][pt] = __builtin_amdgcn_mfma_f32_16x16x32_bf16(ah[nt], bl, acc[nt][pt], 0, 0, 0);
                acc[nt][pt] = __builtin_amdgcn_mfma_f32_16x16x32_bf16(al[nt], bh, acc[nt][pt], 0, 0, 0);
            }
        }
    }

    const int crow = (lane >> 4) * 4;
#pragma unroll
    for (int nt = 0; nt < 2; ++nt)
#pragma unroll
        for (int pt = 0; pt < 4; ++pt)
#pragma unroll
            for (int r = 0; r < 4; ++r) {
                const int n = w * 32 + nt * 16 + crow + r;
                hloc[(size_t)bhc * 8192 + (size_t)n * 64 + pt * 16 + lr] = f2bfu(acc[nt][pt][r]);
            }
}

// ---------------------------------------------------------------------------
// combine: sequential over 32 chunks, bf16 storage, fp32 register recursion.
// ---------------------------------------------------------------------------
__global__ __launch_bounds__(256)
void combine_kernel(unsigned short* __restrict__ hloc,
                    const float* __restrict__ ptot)
{
    const int bid = blockIdx.x;
    const int bh = bid >> 3;
    const int chunk = bid & 7;
    const int e0 = chunk * 1024 + threadIdx.x * 4;

    float s0 = 0.f, s1 = 0.f, s2 = 0.f, s3 = 0.f;
    for (int k = 0; k < NSEG; ++k) {
        unsigned short* p = &hloc[((size_t)bh * NSEG + k) * 8192 + e0];
        const uint2 vp = *(const uint2*)p;
        const float v0 = bfu2f((unsigned short)(vp.x & 0xffff));
        const float v1 = bfu2f((unsigned short)(vp.x >> 16));
        const float v2 = bfu2f((unsigned short)(vp.y & 0xffff));
        const float v3 = bfu2f((unsigned short)(vp.y >> 16));
        uint2 op;
        op.x = (unsigned)f2bfu(s0) | ((unsigned)f2bfu(s1) << 16);
        op.y = (unsigned)f2bfu(s2) | ((unsigned)f2bfu(s3) << 16);
        *(uint2*)p = op;
        const float pt = ptot[bh * NSEG + k];
        s0 = fmaf(pt, s0, v0);
        s1 = fmaf(pt, s1, v1);
        s2 = fmaf(pt, s2, v2);
        s3 = fmaf(pt, s3, v3);
    }
}

// ---------------------------------------------------------------------------
// y: per (b,chunk,headgroup-of-4), 512 thr. Fuses D-skip; writes bf16 y.
// ---------------------------------------------------------------------------
__global__ __launch_bounds__(512)
void y_kernel(const unsigned short* __restrict__ Ch,
              const float* __restrict__ CBg,
              const float* __restrict__ lB,
              const float* __restrict__ dtb,
              const float* __restrict__ xh,
              const unsigned short* __restrict__ hloc,
              const float* __restrict__ dskip,
              unsigned short* __restrict__ ybh)
{
    __shared__ __align__(16) unsigned short CsA[64 * 128];     // C hi [t][n]
    __shared__ __align__(16) unsigned short opB[64 * 128];     // h0T / xT (bf16)
    __shared__ __align__(16) unsigned short Ms[64 * 64];       // M hi [t][s]
    __shared__ float ls4[256], dt4[256];

    const int gid = blockIdx.x;
    const int hg = gid & 3, bc = gid >> 2;
    const int chunk = bc & 31, b = bc >> 5;
    const size_t row0 = (size_t)b * SEQ + (size_t)chunk * TSEG;
    const int tid = threadIdx.x;

    const size_t cbase = (size_t)bc * 8192;
#pragma unroll
    for (int i = 0; i < 2; ++i) {
        const int bi = tid + i * 512;           // 16B block 0..1023
        const int r = bi >> 4, c = (bi & 15) << 3;
        *(uint4*)&CsA[SWZ128(r, c)] = ((const uint4*)(Ch + cbase))[bi];
    }
    if (tid < 256) {
        const int e = tid >> 6, t = tid & 63;
        const int h = hg * 4 + e;
        const int bhc = (b * NHEADS + h) * NSEG + chunk;
        ls4[tid] = lB[(size_t)bhc * 64 + t];
        dt4[tid] = dtb[(row0 + t) * NHEADS + h];
    }
    __syncthreads();

    const int w = tid >> 6, lane = tid & 63;
    const int lr = lane & 15, lk = (lane >> 4) * 8;
    const int tt = w & 3, ph = w >> 2;
    const int crow = (lane >> 4) * 4;
    const float* CBc = CBg + (size_t)bc * 4096;

    for (int e = 0; e < 4; ++e) {
        const int h = hg * 4 + e;
        const int bhc = (b * NHEADS + h) * NSEG + chunk;
        const unsigned short* h0p = hloc + (size_t)bhc * 8192;
        const float dsk = dskip[h];

        // transpose h0 (bf16) -> opB [p][n], direct from global (n-major src)
        {
            const int n = tid & 127;
            const int pb = (tid >> 7) * 16;
            const unsigned short* hr = &h0p[(size_t)n * 64 + pb];
#pragma unroll
            for (int i = 0; i < 16; ++i)
                opB[SWZ128(pb + i, n)] = hr[i];
        }
        __syncthreads();

        // MFMA phase A: acc = C @ h0 (K=128), hi x hi (1 pass)
        f32x4 acc[2];
        acc[0] = (f32x4){0.f, 0.f, 0.f, 0.f};
        acc[1] = (f32x4){0.f, 0.f, 0.f, 0.f};
#pragma unroll
        for (int kk = 0; kk < 4; ++kk) {
            const int k0 = kk * 32;
            const bf16x8 ah = *(const bf16x8*)&CsA[SWZ128(tt * 16 + lr, k0 + lk)];
#pragma unroll
            for (int pt = 0; pt < 2; ++pt) {
                const int pc = (ph * 2 + pt) * 16 + lr;
                const bf16x8 bh = *(const bf16x8*)&opB[SWZ128(pc, k0 + lk)];
                acc[pt] = __builtin_amdgcn_mfma_f32_16x16x32_bf16(ah, bh, acc[pt], 0, 0, 0);
            }
        }
        // row scale by exp(l[t])
        {
            float el[4];
#pragma unroll
            for (int r = 0; r < 4; ++r) el[r] = __expf(ls4[e * 64 + tt * 16 + crow + r]);
#pragma unroll
            for (int pt = 0; pt < 2; ++pt)
#pragma unroll
                for (int r = 0; r < 4; ++r) acc[pt][r] *= el[r];
        }
        __syncthreads();   // phase-A reads of opB done before overwrite

        // form M hi + transpose x -> opB [p][s], direct from global
#pragma unroll
        for (int i = 0; i < 8; ++i) {
            const int lin = tid * 8 + i;
            const int t = lin >> 6, s = lin & 63;
            float m = 0.0f;
            if (s <= t)
                m = CBc[t * 64 + s] * dt4[e * 64 + s] * __expf(ls4[e * 64 + t] - ls4[e * 64 + s]);
            Ms[SWZ64(t, s)] = f2bfu(m);
        }
        {
            const int s = tid & 63;
            const int pb = (tid >> 6) * 8;
            const float* xr = &xh[(row0 + s) * DINNER + h * HEADDIM + pb];
#pragma unroll
            for (int i = 0; i < 8; ++i) {
                const int p = pb + i;
                opB[SWZ64(p, s)] = f2bfu(xr[i]);
            }
        }
        __syncthreads();

        // MFMA phase B: acc += M @ x (K=64), hi x hi (1 pass)
#pragma unroll
        for (int kk = 0; kk < 2; ++kk) {
            const int k0 = kk * 32;
            const bf16x8 ah = *(const bf16x8*)&Ms[SWZ64(tt * 16 + lr, k0 + lk)];
#pragma unroll
            for (int pt = 0; pt < 2; ++pt) {
                const int pc = (ph * 2 + pt) * 16 + lr;
                const bf16x8 bh = *(const bf16x8*)&opB[SWZ64(pc, k0 + lk)];
                acc[pt] = __builtin_amdgcn_mfma_f32_16x16x32_bf16(ah, bh, acc[pt], 0, 0, 0);
            }
        }

        // write y (bf16) with fused D-skip
#pragma unroll
        for (int pt = 0; pt < 2; ++pt)
#pragma unroll
            for (int r = 0; r < 4; ++r) {
                const size_t row = row0 + tt * 16 + crow + r;
                const int col = h * HEADDIM + (ph * 2 + pt) * 16 + lr;
                const float v = acc[pt][r] + dsk * xh[row * DINNER + col];
                ybh[row * DINNER + col] = f2bfu(v);
            }
        __syncthreads();   // opB reads done before next head's overwrite
    }
}

// ---------------------------------------------------------------------------
// Gate + RMSNorm; reads bf16 y and bf16 z; writes ynorm as split-bf16 planes.
// ---------------------------------------------------------------------------
__global__ __launch_bounds__(256)
void gate_kernel(const unsigned short* __restrict__ ybh,
                 const unsigned short* __restrict__ zxh,
                 const float* __restrict__ nw,
                 unsigned short* __restrict__ yh,
                 unsigned short* __restrict__ yl)
{
    const int row = blockIdx.x;
    const int c4 = threadIdx.x * 4;

    const uint2 yv = *(const uint2*)&ybh[(size_t)row * DINNER + c4];
    float4 y;
    y.x = bfu2f((unsigned short)(yv.x & 0xffff));
    y.y = bfu2f((unsigned short)(yv.x >> 16));
    y.z = bfu2f((unsigned short)(yv.y & 0xffff));
    y.w = bfu2f((unsigned short)(yv.y >> 16));

    const uint2 zv = *(const uint2*)&zxh[(size_t)row * DINPROJ + c4];
    float4 z;
    z.x = bfu2f((unsigned short)(zv.x & 0xffff));
    z.y = bfu2f((unsigned short)(zv.x >> 16));
    z.z = bfu2f((unsigned short)(zv.y & 0xffff));
    z.w = bfu2f((unsigned short)(zv.y >> 16));

    float4 g;
    g.x = y.x * silu_f(z.x);
    g.y = y.y * silu_f(z.y);
    g.z = y.z * silu_f(z.z);
    g.w = y.w * silu_f(z.w);

    float local = g.x * g.x + g.y * g.y + g.z * g.z + g.w * g.w;
#pragma unroll
    for (int m = 32; m >= 1; m >>= 1) local += __shfl_xor(local, m, 64);

    __shared__ float red[4];
    if ((threadIdx.x & 63) == 0) red[threadIdx.x >> 6] = local;
    __syncthreads();
    const float total = red[0] + red[1] + red[2] + red[3];
    const float scale = rsqrtf(total * (1.0f / (float)DINNER) + 1e-5f);

    const float4 w = *(const float4*)&nw[c4];
    float o[4];
    o[0] = g.x * scale * w.x;
    o[1] = g.y * scale * w.y;
    o[2] = g.z * scale * w.z;
    o[3] = g.w * scale * w.w;

    unsigned hv[4], lv[4];
#pragma unroll
    for (int j = 0; j < 4; ++j) {
        hv[j] = f2bfu(o[j]);
        lv[j] = f2bfu(o[j] - bfu2f((unsigned short)hv[j]));
    }
    const size_t oi = (size_t)row * DINNER + c4;
    *(uint2*)&yh[oi] = make_uint2(hv[0] | (hv[1] << 16), hv[2] | (hv[3] << 16));
    *(uint2*)&yl[oi] = make_uint2(lv[0] | (lv[1] << 16), lv[2] | (lv[3] << 16));
}

// ---------------------------------------------------------------------------
extern "C" void kernel_launch(void* const* d_in, const int* in_sizes, int n_in,
                              void* d_out, int out_size, void* d_ws, size_t ws_size,
                              hipStream_t stream)
{
    const float* x_in    = (const float*)d_in[0];
    const float* in_w    = (const float*)d_in[1];
    const float* conv_w  = (const float*)d_in[2];
    const float* conv_b  = (const float*)d_in[3];
    const float* dt_bias = (const float*)d_in[4];
    const float* A_log   = (const float*)d_in[5];
    const float* D_skip  = (const float*)d_in[6];
    const float* norm_w  = (const float*)d_in[7];
    const float* out_w   = (const float*)d_in[8];
    float* out = (float*)d_out;

    float* ws   = (float*)d_ws;
    float* zx   = ws;                               // region 19,005,440 f (zx bf16 + dtraw)
    float* xh   = zx   + (size_t)ROWS * DINPROJ;    //  8,388,608 f
    float* Bb   = xh   + (size_t)ROWS * DINNER;     //  1,048,576 f (unused)
    float* Cb   = Bb   + (size_t)ROWS * DSTATE;     //  1,048,576 f (unused)
    float* dtb  = Cb   + (size_t)ROWS * DSTATE;     //    131,072 f
    float* dAb  = dtb  + (size_t)ROWS * NHEADS;     //    131,072 f
    float* yb   = dAb  + (size_t)ROWS * NHEADS;     //  8,388,608 f (bf16 y lives here)
    float* UN   = yb   + (size_t)ROWS * DINNER;     // 16,777,216 f (union)
    float* BtF  = UN   + (size_t)16777216;          //  1,245,184 f
    float* WtF  = BtF  + (size_t)1245184;           //    524,288 f
    float* ptot = WtF  + (size_t)524288;            //      2,048 f
    float* lB   = ptot + (size_t)2048;              //    131,072 f
    float* wB   = lB   + (size_t)131072;            //    131,072 f
    float* BTf  = wB   + (size_t)131072;            //  1,048,576 f
    float* Bspf = BTf  + (size_t)1048576;           //  1,048,576 f
    float* Cspf = Bspf + (size_t)1048576;           //  1,048,576 f
    float* CBb  = Cspf + (size_t)1048576;           //    524,288 f
    // total 60,622,848 f = 242.5 MB

    unsigned short* zxh = (unsigned short*)zx;                // bf16 [8192][2320]
    float* dtraw = zx + 10485760;                             // fp32 [8192][16]
    unsigned short* ybh = (unsigned short*)yb;                // bf16 y [8192][1024]
    unsigned short* hloc_us = (unsigned short*)UN;            // [0 .. 8.39M)
    unsigned short* yh = (unsigned short*)UN;                 // [0 .. 8.39M)
    unsigned short* yl = yh + (size_t)ROWS * DINNER;          // [8.39M .. 16.78M)
    unsigned short* Ah = (unsigned short*)UN + 16777216;      // [16.78M .. 20.97M)
    unsigned short* Al = Ah + (size_t)ROWS * DMODEL;          // [20.97M .. 25.17M)

    unsigned short* Bth = (unsigned short*)BtF;               // [2432][512]
    unsigned short* Btl = Bth + (size_t)NPAD_IN * DMODEL;
    unsigned short* Wth = (unsigned short*)WtF;               // [512][1024]
    unsigned short* Wtl = Wth + (size_t)DMODEL * DINNER;

    unsigned short* BTh = (unsigned short*)BTf;               // [128][128][64]
    unsigned short* BTl = BTh + (size_t)128 * 8192;
    unsigned short* Bsph = (unsigned short*)Bspf;             // [8192][128]
    unsigned short* Bspl = Bsph + (size_t)ROWS * DSTATE;
    unsigned short* Csph = (unsigned short*)Cspf;             // [8192][128]
    unsigned short* Cspl = Csph + (size_t)ROWS * DSTATE;

    for (int layer = 0; layer < 2; ++layer) {
        if (layer == 0)
            split_a_kernel<<<(ROWS * DMODEL) / (256 * 8), 256, 0, stream>>>(x_in, Ah, Al);
        // layer 1: Ah/Al already written by layer-0 out-proj epilogue

        tsplit_w_kernel<<<dim3(NPAD_IN / 32, DMODEL / 32), 256, 0, stream>>>(
            in_w + (size_t)layer * DMODEL * DINPROJ, DMODEL, DINPROJ, Bth, Btl);

        gemm_bf16s<<<dim3(NPAD_IN / 128, ROWS / 128), 256, 0, stream>>>(
            Ah, Al, Bth, Btl, nullptr, zxh, DINPROJ, DINPROJ, DMODEL,
            DINNER + CONVDIM, dtraw, nullptr, nullptr);

        conv_kernel<<<ROWS, CONVDIM / 4, 0, stream>>>(
            zxh, dtraw,
            conv_w + (size_t)layer * DCONV * CONVDIM,
            conv_b + (size_t)layer * CONVDIM,
            dt_bias + (size_t)layer * NHEADS,
            A_log + (size_t)layer * NHEADS,
            xh, Bsph, Bspl, Csph, Cspl, dtb, dAb);

        meta_kernel<<<BATCH * NHEADS * NSEG, 64, 0, stream>>>(
            dtb, A_log + (size_t)layer * NHEADS, lB, wB, ptot);

        tsplit_bf16_kernel<<<BATCH * NSEG * 2, 256, 0, stream>>>(
            Bsph, Bspl, BTh, BTl);

        cb_kernel<<<BATCH * NSEG, 256, 0, stream>>>(Csph, Cspl, Bsph, Bspl, CBb);

        state_kernel<<<BATCH * NHEADS * NSEG, 256, 0, stream>>>(
            BTh, BTl, xh, wB, hloc_us);

        combine_kernel<<<BATCH * NHEADS * 8, 256, 0, stream>>>(hloc_us, ptot);

        y_kernel<<<BATCH * NSEG * 4, 512, 0, stream>>>(
            Csph, CBb, lB, dtb, xh, hloc_us,
            D_skip + (size_t)layer * NHEADS, ybh);

        gate_kernel<<<ROWS, 256, 0, stream>>>(
            ybh, zxh, norm_w + (size_t)layer * DINNER, yh, yl);

        tsplit_w_kernel<<<dim3(DMODEL / 32, DINNER / 32), 256, 0, stream>>>(
            out_w + (size_t)layer * DINNER * DMODEL, DINNER, DMODEL, Wth, Wtl);

        gemm_bf16s<<<dim3(DMODEL / 128, ROWS / 128), 256, 0, stream>>>(
            yh, yl, Wth, Wtl, out, nullptr, DMODEL, DMODEL, DINNER,
            1 << 30, nullptr,
            (layer == 0) ? Ah : nullptr,
            (layer == 0) ? Al : nullptr);
    }
}

// Round 25
// 423.919 us; speedup vs baseline: 1.0468x; 1.0468x over previous
//
#include <hip/hip_runtime.h>
#include <hip/hip_bf16.h>
#include <cstddef>
#include <cstdint>

// Mamba2 (2 layers). Round-25: out-proj switched to a 128x64-tile GEMM
// (gemm_bf16s_n64): grid 256->512 blocks (2/CU), LDS 64->48KB, acc halved.
// In-proj keeps the 128x128 dbuf kernel (round-24, verified 443 us).

#define BATCH 4
#define SEQ   2048
#define DMODEL 512
#define DINNER 1024
#define DSTATE 128
#define HEADDIM 64
#define NHEADS 16
#define DCONV 4
#define CONVDIM 1280
#define DINPROJ 2320
#define NPAD_IN 2432          // 19 * 128
#define ROWS (BATCH * SEQ)    // 8192
#define NSEG 32               // chunks per sequence
#define TSEG 64               // chunk length

#define SWZ32(r, c)  ((r) * 32  + (((((c) >> 3) ^ (((r) >> 1) & 3)) << 3) | ((c) & 7)))
#define SWZ64(r, c)  ((r) * 64  + (((((c) >> 3) ^ ((r) & 7)) << 3) | ((c) & 7)))
#define SWZ128(r, c) ((r) * 128 + (((((c) >> 3) ^ ((r) & 7)) << 3) | ((c) & 7)))

typedef __attribute__((ext_vector_type(8))) short bf16x8;
typedef __attribute__((ext_vector_type(4))) float f32x4;

__device__ __forceinline__ float silu_f(float x) {
    return x * (1.0f / (1.0f + __expf(-x)));
}
__device__ __forceinline__ unsigned short f2bfu(float f) {  // RNE fp32->bf16
    unsigned u = __float_as_uint(f);
    unsigned r = u + 0x7FFFu + ((u >> 16) & 1u);
    return (unsigned short)(r >> 16);
}
__device__ __forceinline__ float bfu2f(unsigned short h) {
    return __uint_as_float(((unsigned)h) << 16);
}

// ---------------------------------------------------------------------------
// Split fp32 flat array -> hi/lo bf16. 8 elems/thread. (layer-0 x only)
// ---------------------------------------------------------------------------
__global__ __launch_bounds__(256)
void split_a_kernel(const float* __restrict__ A,
                    unsigned short* __restrict__ Ah,
                    unsigned short* __restrict__ Al)
{
    const size_t i = ((size_t)blockIdx.x * 256 + threadIdx.x) * 8;
    const float4 a = *(const float4*)&A[i];
    const float4 b = *(const float4*)&A[i + 4];
    float v[8] = {a.x, a.y, a.z, a.w, b.x, b.y, b.z, b.w};
    unsigned hv[8], lv[8];
#pragma unroll
    for (int j = 0; j < 8; ++j) {
        hv[j] = f2bfu(v[j]);
        lv[j] = f2bfu(v[j] - bfu2f((unsigned short)hv[j]));
    }
    uint4 ph = make_uint4(hv[0] | (hv[1] << 16), hv[2] | (hv[3] << 16),
                          hv[4] | (hv[5] << 16), hv[6] | (hv[7] << 16));
    uint4 pl = make_uint4(lv[0] | (lv[1] << 16), lv[2] | (lv[3] << 16),
                          lv[4] | (lv[5] << 16), lv[6] | (lv[7] << 16));
    *(uint4*)&Ah[i] = ph;
    *(uint4*)&Al[i] = pl;
}

// ---------------------------------------------------------------------------
// Transpose + split weight W[K][N] fp32 -> Oh/Ol[Npad][K] bf16 (n >= N -> 0).
// ---------------------------------------------------------------------------
__global__ __launch_bounds__(256)
void tsplit_w_kernel(const float* __restrict__ W, int K, int N,
                     unsigned short* __restrict__ Oh,
                     unsigned short* __restrict__ Ol)
{
    __shared__ float tile[32][33];
    const int n0 = blockIdx.x * 32, k0 = blockIdx.y * 32;
    const int c = threadIdx.x & 31, r8 = threadIdx.x >> 5;
    const int n = n0 + c;
#pragma unroll
    for (int i = 0; i < 4; ++i) {
        const int k = r8 + i * 8;
        float v = 0.0f;
        if (n < N) v = W[(size_t)(k0 + k) * N + n];
        tile[c][k] = v;
    }
    __syncthreads();
#pragma unroll
    for (int i = 0; i < 4; ++i) {
        const int nl = r8 + i * 8;
        const float v = tile[nl][c];
        const unsigned short h = f2bfu(v);
        const unsigned short l = f2bfu(v - bfu2f(h));
        const size_t o = (size_t)(n0 + nl) * K + k0 + c;
        Oh[o] = h;
        Ol[o] = l;
    }
}

// ---------------------------------------------------------------------------
// Transpose bf16 B planes: per (chunk, plane), [64 t][128 n] -> [128 n][64 t].
// ---------------------------------------------------------------------------
__global__ __launch_bounds__(256)
void tsplit_bf16_kernel(const unsigned short* __restrict__ S0,
                        const unsigned short* __restrict__ S1,
                        unsigned short* __restrict__ O0,
                        unsigned short* __restrict__ O1)
{
    __shared__ unsigned short tile[64][136];
    const int z = blockIdx.x;
    const int chunk = z >> 1, plane = z & 1;
    const unsigned short* S = plane ? S1 : S0;
    unsigned short* O = plane ? O1 : O0;
    const size_t base = (size_t)chunk * TSEG * DSTATE;
    const int tid = threadIdx.x;

#pragma unroll
    for (int i = 0; i < 4; ++i) {
        const int e8 = tid + i * 256;       // 8-ushort block 0..1023
        const int t = e8 >> 4;
        const int n = (e8 & 15) * 8;
        *(uint4*)&tile[t][n] = *(const uint4*)&S[base + (size_t)t * DSTATE + n];
    }
    __syncthreads();

    const int n = tid & 127;
    const int th = (tid >> 7) * 32;
#pragma unroll
    for (int i = 0; i < 4; ++i) {
        uint4 o;
        o.x = (unsigned)tile[th + i * 8 + 0][n] | ((unsigned)tile[th + i * 8 + 1][n] << 16);
        o.y = (unsigned)tile[th + i * 8 + 2][n] | ((unsigned)tile[th + i * 8 + 3][n] << 16);
        o.z = (unsigned)tile[th + i * 8 + 4][n] | ((unsigned)tile[th + i * 8 + 5][n] << 16);
        o.w = (unsigned)tile[th + i * 8 + 6][n] | ((unsigned)tile[th + i * 8 + 7][n] << 16);
        *(uint4*)&O[(size_t)chunk * 8192 + (size_t)n * 64 + th + i * 8] = o;
    }
}

// ---------------------------------------------------------------------------
// Split-bf16 MFMA GEMM, 128x128 tile, double-buffered LDS (in-proj).
// ---------------------------------------------------------------------------
__global__ __launch_bounds__(256)
void gemm_bf16s(const unsigned short* __restrict__ Ah,
                const unsigned short* __restrict__ Al,
                const unsigned short* __restrict__ Bh,
                const unsigned short* __restrict__ Bl,
                float* __restrict__ Cf,
                unsigned short* __restrict__ Cbh,
                int ldc, int N, int K,
                int exactCol0,
                float* __restrict__ dtf,
                unsigned short* __restrict__ Soh,
                unsigned short* __restrict__ Sol)
{
    __shared__ __align__(16) unsigned short As[2][2][128 * 32];  // [plane][buf]
    __shared__ __align__(16) unsigned short Bs[2][2][128 * 32];

    const int tid = threadIdx.x;
    const int w = tid >> 6, lane = tid & 63;
    const int wm = w >> 1, wn = w & 1;

    const int nwg = gridDim.x * gridDim.y;
    int flat = blockIdx.y * gridDim.x + blockIdx.x;
    flat = (flat & 7) * (nwg >> 3) + (flat >> 3);
    const int bx = flat % gridDim.x, by = flat / gridDim.x;
    const int row0 = by * 128, col0 = bx * 128;
    const bool exact = (col0 + 128 > exactCol0);

    const int srow = tid >> 1;
    const int sk   = (tid & 1) * 16;

    const int lr = lane & 15;
    const int lk = (lane >> 4) * 8;

    f32x4 acc[4][4];
#pragma unroll
    for (int i = 0; i < 4; ++i)
#pragma unroll
        for (int j = 0; j < 4; ++j) acc[i][j] = (f32x4){0.f, 0.f, 0.f, 0.f};

    const int sw0 = SWZ32(srow, sk);
    const int sw1 = SWZ32(srow, sk + 8);
    const size_t gabase = (size_t)(row0 + srow) * K + sk;
    const size_t gbbase = (size_t)(col0 + srow) * K + sk;

    uint4 vah0 = *(const uint4*)&Ah[gabase];
    uint4 vah1 = *(const uint4*)&Ah[gabase + 8];
    uint4 val0 = *(const uint4*)&Al[gabase];
    uint4 val1 = *(const uint4*)&Al[gabase + 8];
    uint4 vbh0 = *(const uint4*)&Bh[gbbase];
    uint4 vbh1 = *(const uint4*)&Bh[gbbase + 8];
    uint4 vbl0, vbl1;
    if (exact) {
        vbl0 = *(const uint4*)&Bl[gbbase];
        vbl1 = *(const uint4*)&Bl[gbbase + 8];
    }

    int cur = 0;
    for (int k0 = 0; k0 < K; k0 += 32) {
        *(uint4*)&As[0][cur][sw0] = vah0;  *(uint4*)&As[0][cur][sw1] = vah1;
        *(uint4*)&As[1][cur][sw0] = val0;  *(uint4*)&As[1][cur][sw1] = val1;
        *(uint4*)&Bs[0][cur][sw0] = vbh0;  *(uint4*)&Bs[0][cur][sw1] = vbh1;
        if (exact) {
            *(uint4*)&Bs[1][cur][sw0] = vbl0;
            *(uint4*)&Bs[1][cur][sw1] = vbl1;
        }
        __syncthreads();

        if (k0 + 32 < K) {
            const size_t ga = gabase + k0 + 32;
            const size_t gb = gbbase + k0 + 32;
            vah0 = *(const uint4*)&Ah[ga];
            vah1 = *(const uint4*)&Ah[ga + 8];
            val0 = *(const uint4*)&Al[ga];
            val1 = *(const uint4*)&Al[ga + 8];
            vbh0 = *(const uint4*)&Bh[gb];
            vbh1 = *(const uint4*)&Bh[gb + 8];
            if (exact) {
                vbl0 = *(const uint4*)&Bl[gb];
                vbl1 = *(const uint4*)&Bl[gb + 8];
            }
        }

        bf16x8 a_h[4], a_l[4], b_h[4];
#pragma unroll
        for (int mt = 0; mt < 4; ++mt) {
            const int r = wm * 64 + mt * 16 + lr;
            a_h[mt] = *(const bf16x8*)&As[0][cur][SWZ32(r, lk)];
            a_l[mt] = *(const bf16x8*)&As[1][cur][SWZ32(r, lk)];
        }
#pragma unroll
        for (int nt = 0; nt < 4; ++nt) {
            const int c = wn * 64 + nt * 16 + lr;
            b_h[nt] = *(const bf16x8*)&Bs[0][cur][SWZ32(c, lk)];
        }
#pragma unroll
        for (int mt = 0; mt < 4; ++mt)
#pragma unroll
            for (int nt = 0; nt < 4; ++nt) {
                acc[mt][nt] = __builtin_amdgcn_mfma_f32_16x16x32_bf16(a_h[mt], b_h[nt], acc[mt][nt], 0, 0, 0);
                acc[mt][nt] = __builtin_amdgcn_mfma_f32_16x16x32_bf16(a_l[mt], b_h[nt], acc[mt][nt], 0, 0, 0);
            }
        if (exact) {
            bf16x8 b_l[4];
#pragma unroll
            for (int nt = 0; nt < 4; ++nt) {
                const int c = wn * 64 + nt * 16 + lr;
                b_l[nt] = *(const bf16x8*)&Bs[1][cur][SWZ32(c, lk)];
            }
#pragma unroll
            for (int mt = 0; mt < 4; ++mt)
#pragma unroll
                for (int nt = 0; nt < 4; ++nt)
                    acc[mt][nt] = __builtin_amdgcn_mfma_f32_16x16x32_bf16(a_h[mt], b_l[nt], acc[mt][nt], 0, 0, 0);
        }
        cur ^= 1;
    }

    const int crow = (lane >> 4) * 4;
#pragma unroll
    for (int mt = 0; mt < 4; ++mt)
#pragma unroll
        for (int nt = 0; nt < 4; ++nt) {
            const int cc = col0 + wn * 64 + nt * 16 + lr;
            if (cc < N) {
#pragma unroll
                for (int r = 0; r < 4; ++r) {
                    const size_t row = (size_t)(row0 + wm * 64 + mt * 16 + crow + r);
                    const float v = acc[mt][nt][r];
                    if (Cf) {
                        const size_t oi = row * ldc + cc;
                        Cf[oi] = v;
                        if (Soh) {
                            const unsigned short h16 = f2bfu(v);
                            Soh[oi] = h16;
                            Sol[oi] = f2bfu(v - bfu2f(h16));
                        }
                    } else {
                        if (cc >= exactCol0)
                            dtf[row * NHEADS + (cc - exactCol0)] = v;
                        else
                            Cbh[row * ldc + cc] = f2bfu(v);
                    }
                }
            }
        }
}

// ---------------------------------------------------------------------------
// Split-bf16 MFMA GEMM, 128x64 tile (out-proj: small-N, 2x grid, 48KB LDS).
// Same dbuf structure and K-order as gemm_bf16s -> bit-identical results.
// ---------------------------------------------------------------------------
__global__ __launch_bounds__(256)
void gemm_bf16s_n64(const unsigned short* __restrict__ Ah,
                    const unsigned short* __restrict__ Al,
                    const unsigned short* __restrict__ Bh,
                    float* __restrict__ Cf,
                    int ldc, int N, int K,
                    unsigned short* __restrict__ Soh,
                    unsigned short* __restrict__ Sol)
{
    __shared__ __align__(16) unsigned short As[2][2][128 * 32];  // [plane][buf]
    __shared__ __align__(16) unsigned short Bs[2][64 * 32];      // [buf] hi only

    const int tid = threadIdx.x;
    const int w = tid >> 6, lane = tid & 63;
    const int wm = w >> 1, wn = w & 1;

    const int nwg = gridDim.x * gridDim.y;
    int flat = blockIdx.y * gridDim.x + blockIdx.x;
    flat = (flat & 7) * (nwg >> 3) + (flat >> 3);
    const int bx = flat % gridDim.x, by = flat / gridDim.x;
    const int row0 = by * 128, col0 = bx * 64;

    const int srow = tid >> 1;
    const int sk   = (tid & 1) * 16;
    const int brow = tid >> 2;              // 0..63
    const int bk   = (tid & 3) * 8;         // 0,8,16,24

    const int lr = lane & 15;
    const int lk = (lane >> 4) * 8;

    f32x4 acc[4][2];
#pragma unroll
    for (int i = 0; i < 4; ++i)
#pragma unroll
        for (int j = 0; j < 2; ++j) acc[i][j] = (f32x4){0.f, 0.f, 0.f, 0.f};

    const int sw0 = SWZ32(srow, sk);
    const int sw1 = SWZ32(srow, sk + 8);
    const int swb = SWZ32(brow, bk);
    const size_t gabase = (size_t)(row0 + srow) * K + sk;
    const size_t gbbase = (size_t)(col0 + brow) * K + bk;

    uint4 vah0 = *(const uint4*)&Ah[gabase];
    uint4 vah1 = *(const uint4*)&Ah[gabase + 8];
    uint4 val0 = *(const uint4*)&Al[gabase];
    uint4 val1 = *(const uint4*)&Al[gabase + 8];
    uint4 vbh0 = *(const uint4*)&Bh[gbbase];

    int cur = 0;
    for (int k0 = 0; k0 < K; k0 += 32) {
        *(uint4*)&As[0][cur][sw0] = vah0;  *(uint4*)&As[0][cur][sw1] = vah1;
        *(uint4*)&As[1][cur][sw0] = val0;  *(uint4*)&As[1][cur][sw1] = val1;
        *(uint4*)&Bs[cur][swb] = vbh0;
        __syncthreads();

        if (k0 + 32 < K) {
            const size_t ga = gabase + k0 + 32;
            vah0 = *(const uint4*)&Ah[ga];
            vah1 = *(const uint4*)&Ah[ga + 8];
            val0 = *(const uint4*)&Al[ga];
            val1 = *(const uint4*)&Al[ga + 8];
            vbh0 = *(const uint4*)&Bh[gbbase + k0 + 32];
        }

        bf16x8 a_h[4], a_l[4], b_h[2];
#pragma unroll
        for (int mt = 0; mt < 4; ++mt) {
            const int r = wm * 64 + mt * 16 + lr;
            a_h[mt] = *(const bf16x8*)&As[0][cur][SWZ32(r, lk)];
            a_l[mt] = *(const bf16x8*)&As[1][cur][SWZ32(r, lk)];
        }
#pragma unroll
        for (int nt = 0; nt < 2; ++nt) {
            const int c = wn * 32 + nt * 16 + lr;
            b_h[nt] = *(const bf16x8*)&Bs[cur][SWZ32(c, lk)];
        }
#pragma unroll
        for (int mt = 0; mt < 4; ++mt)
#pragma unroll
            for (int nt = 0; nt < 2; ++nt) {
                acc[mt][nt] = __builtin_amdgcn_mfma_f32_16x16x32_bf16(a_h[mt], b_h[nt], acc[mt][nt], 0, 0, 0);
                acc[mt][nt] = __builtin_amdgcn_mfma_f32_16x16x32_bf16(a_l[mt], b_h[nt], acc[mt][nt], 0, 0, 0);
            }
        cur ^= 1;
    }

    const int crow = (lane >> 4) * 4;
#pragma unroll
    for (int mt = 0; mt < 4; ++mt)
#pragma unroll
        for (int nt = 0; nt < 2; ++nt) {
            const int cc = col0 + wn * 32 + nt * 16 + lr;
            if (cc < N) {
#pragma unroll
                for (int r = 0; r < 4; ++r) {
                    const size_t row = (size_t)(row0 + wm * 64 + mt * 16 + crow + r);
                    const float v = acc[mt][nt][r];
                    const size_t oi = row * ldc + cc;
                    Cf[oi] = v;
                    if (Soh) {
                        const unsigned short h16 = f2bfu(v);
                        Soh[oi] = h16;
                        Sol[oi] = f2bfu(v - bfu2f(h16));
                    }
                }
            }
        }
}

// ---------------------------------------------------------------------------
// Depthwise causal conv (4 taps) + bias + SiLU + dt/dA precompute.
// ---------------------------------------------------------------------------
__global__ __launch_bounds__(320)
void conv_kernel(const unsigned short* __restrict__ zxh,
                 const float* __restrict__ dtraw,
                 const float* __restrict__ cw,
                 const float* __restrict__ cb,
                 const float* __restrict__ dtbias,
                 const float* __restrict__ alog,
                 float* __restrict__ xh,
                 unsigned short* __restrict__ Bsph,
                 unsigned short* __restrict__ Bspl,
                 unsigned short* __restrict__ Csph,
                 unsigned short* __restrict__ Cspl,
                 float* __restrict__ dtb,
                 float* __restrict__ dAb)
{
    const int row = blockIdx.x;
    const int l   = row & (SEQ - 1);
    const int c4  = threadIdx.x * 4;

    float4 acc = *(const float4*)&cb[c4];
#pragma unroll
    for (int k = 0; k < DCONV; ++k) {
        const int lk = l - (DCONV - 1) + k;
        if (lk >= 0) {
            const uint2 vv = *(const uint2*)&zxh[(size_t)(row - (DCONV - 1) + k) * DINPROJ + DINNER + c4];
            float4 v;
            v.x = bfu2f((unsigned short)(vv.x & 0xffff));
            v.y = bfu2f((unsigned short)(vv.x >> 16));
            v.z = bfu2f((unsigned short)(vv.y & 0xffff));
            v.w = bfu2f((unsigned short)(vv.y >> 16));
            const float4 w = *(const float4*)&cw[k * CONVDIM + c4];
            acc.x = fmaf(v.x, w.x, acc.x);
            acc.y = fmaf(v.y, w.y, acc.y);
            acc.z = fmaf(v.z, w.z, acc.z);
            acc.w = fmaf(v.w, w.w, acc.w);
        }
    }
    acc.x = silu_f(acc.x);
    acc.y = silu_f(acc.y);
    acc.z = silu_f(acc.z);
    acc.w = silu_f(acc.w);

    if (c4 < DINNER) {
        *(float4*)&xh[(size_t)row * DINNER + c4] = acc;
    } else {
        float o[4] = {acc.x, acc.y, acc.z, acc.w};
        unsigned hv[4], lv[4];
#pragma unroll
        for (int j = 0; j < 4; ++j) {
            hv[j] = f2bfu(o[j]);
            lv[j] = f2bfu(o[j] - bfu2f((unsigned short)hv[j]));
        }
        const uint2 ph = make_uint2(hv[0] | (hv[1] << 16), hv[2] | (hv[3] << 16));
        const uint2 pl = make_uint2(lv[0] | (lv[1] << 16), lv[2] | (lv[3] << 16));
        if (c4 < DINNER + DSTATE) {
            const size_t oi = (size_t)row * DSTATE + (c4 - DINNER);
            *(uint2*)&Bsph[oi] = ph;
            *(uint2*)&Bspl[oi] = pl;
        } else {
            const size_t oi = (size_t)row * DSTATE + (c4 - DINNER - DSTATE);
            *(uint2*)&Csph[oi] = ph;
            *(uint2*)&Cspl[oi] = pl;
        }
    }

    if (threadIdx.x < NHEADS) {
        const int hh = threadIdx.x;
        const float raw = dtraw[(size_t)row * NHEADS + hh] + dtbias[hh];
        const float dtv = (raw > 20.0f) ? raw : log1pf(expf(raw));
        const float a = expf(alog[hh]);
        dtb[row * NHEADS + hh] = dtv;
        dAb[row * NHEADS + hh] = expf(-a * dtv);
    }
}

// ---------------------------------------------------------------------------
// meta: per (b,h,chunk) wave: l[t] = inclusive cumsum(-a*dt); w; ptot.
// ---------------------------------------------------------------------------
__global__ __launch_bounds__(64)
void meta_kernel(const float* __restrict__ dtb,
                 const float* __restrict__ alog,
                 float* __restrict__ lB, float* __restrict__ wB,
                 float* __restrict__ ptot)
{
    const int bhc = blockIdx.x;
    const int chunk = bhc & 31;
    const int h = (bhc >> 5) & 15;
    const int b = bhc >> 9;
    const int t = threadIdx.x;
    const size_t row0 = (size_t)b * SEQ + (size_t)chunk * TSEG;

    const float a = __expf(alog[h]);
    const float dtv = dtb[(row0 + t) * NHEADS + h];
    float v = -a * dtv;
#pragma unroll
    for (int off = 1; off < 64; off <<= 1) {
        const float u = __shfl_up(v, off, 64);
        if (t >= off) v += u;
    }
    const float l63 = __shfl(v, 63, 64);
    lB[(size_t)bhc * 64 + t] = v;
    wB[(size_t)bhc * 64 + t] = __expf(l63 - v) * dtv;
    if (t == 0) ptot[bhc] = __expf(l63);
}

// ---------------------------------------------------------------------------
// cb: CB[t][s] = C_chunk @ B_chunk^T per (b,chunk). Swizzled (SWZ128).
// ---------------------------------------------------------------------------
__global__ __launch_bounds__(256)
void cb_kernel(const unsigned short* __restrict__ Ch,
               const unsigned short* __restrict__ Cl,
               const unsigned short* __restrict__ Bh_,
               const unsigned short* __restrict__ Bl_,
               float* __restrict__ CBo)
{
    __shared__ __align__(16) unsigned short Cs[2][64 * 128];
    __shared__ __align__(16) unsigned short Bs2[2][64 * 128];
    const int bc = blockIdx.x;
    const size_t base = (size_t)bc * 8192;
    const int tid = threadIdx.x;
#pragma unroll
    for (int i = 0; i < 4; ++i) {
        const int bi = tid + i * 256;           // 16B block 0..1023
        const int r = bi >> 4, c = (bi & 15) << 3;
        const int d = SWZ128(r, c);
        *(uint4*)&Cs[0][d]  = ((const uint4*)(Ch  + base))[bi];
        *(uint4*)&Cs[1][d]  = ((const uint4*)(Cl  + base))[bi];
        *(uint4*)&Bs2[0][d] = ((const uint4*)(Bh_ + base))[bi];
        *(uint4*)&Bs2[1][d] = ((const uint4*)(Bl_ + base))[bi];
    }
    __syncthreads();

    const int w = tid >> 6, lane = tid & 63;
    const int lr = lane & 15, lk = (lane >> 4) * 8;
    f32x4 acc[4];
#pragma unroll
    for (int i = 0; i < 4; ++i) acc[i] = (f32x4){0.f, 0.f, 0.f, 0.f};

#pragma unroll
    for (int kk = 0; kk < 4; ++kk) {
        const int k0 = kk * 32;
        const int ar = w * 16 + lr;
        const bf16x8 ah = *(const bf16x8*)&Cs[0][SWZ128(ar, k0 + lk)];
        const bf16x8 al = *(const bf16x8*)&Cs[1][SWZ128(ar, k0 + lk)];
#pragma unroll
        for (int st = 0; st < 4; ++st) {
            const int br = st * 16 + lr;
            const bf16x8 bh = *(const bf16x8*)&Bs2[0][SWZ128(br, k0 + lk)];
            const bf16x8 bl = *(const bf16x8*)&Bs2[1][SWZ128(br, k0 + lk)];
            acc[st] = __builtin_amdgcn_mfma_f32_16x16x32_bf16(ah, bh, acc[st], 0, 0, 0);
            acc[st] = __builtin_amdgcn_mfma_f32_16x16x32_bf16(ah, bl, acc[st], 0, 0, 0);
            acc[st] = __builtin_amdgcn_mfma_f32_16x16x32_bf16(al, bh, acc[st], 0, 0, 0);
        }
    }
    const int crow = (lane >> 4) * 4;
#pragma unroll
    for (int st = 0; st < 4; ++st)
#pragma unroll
        for (int r = 0; r < 4; ++r)
            CBo[(size_t)bc * 4096 + (size_t)(w * 16 + crow + r) * 64 + st * 16 + lr] = acc[st][r];
}

// ---------------------------------------------------------------------------
// state: S[n][p] = sum_t (B[t,n]*w[t]) * x[t,p] per (b,h,chunk). Swizzled.
// Writes bf16 states.
// ---------------------------------------------------------------------------
__global__ __launch_bounds__(256)
void state_kernel(const unsigned short* __restrict__ BTh,
                  const unsigned short* __restrict__ BTl,
                  const float* __restrict__ xh,
                  const float* __restrict__ wB,
                  unsigned short* __restrict__ hloc)
{
    __shared__ __align__(16) unsigned short BTs[2][128 * 64];
    __shared__ __align__(16) unsigned short xwT[2][64 * 64];

    const int bhc = blockIdx.x;
    const int chunk = bhc & 31;
    const int h = (bhc >> 5) & 15;
    const int b = bhc >> 9;
    const int bc = b * 32 + chunk;
    const size_t row0 = (size_t)b * SEQ + (size_t)chunk * TSEG;
    const int tid = threadIdx.x;

    const size_t bbase = (size_t)bc * 8192;
#pragma unroll
    for (int i = 0; i < 4; ++i) {
        const int bi = tid + i * 256;           // 16B block 0..1023
        const int r = bi >> 3, c = (bi & 7) << 3;
        const int d = SWZ64(r, c);
        *(uint4*)&BTs[0][d] = ((const uint4*)(BTh + bbase))[bi];
        *(uint4*)&BTs[1][d] = ((const uint4*)(BTl + bbase))[bi];
    }
    {
        const int t = tid & 63;
        const int pb = (tid >> 6) * 16;
        const float wv = wB[(size_t)bhc * 64 + t];
        const float* xr = &xh[(row0 + t) * DINNER + h * HEADDIM + pb];
#pragma unroll
        for (int i = 0; i < 16; ++i) {
            const int p = pb + i;
            const float v = xr[i] * wv;
            const unsigned short hh = f2bfu(v);
            const int d = SWZ64(p, t);
            xwT[0][d] = hh;
            xwT[1][d] = f2bfu(v - bfu2f(hh));
        }
    }
    __syncthreads();

    const int w = tid >> 6, lane = tid & 63;
    const int lr = lane & 15, lk = (lane >> 4) * 8;
    f32x4 acc[2][4];
#pragma unroll
    for (int i = 0; i < 2; ++i)
#pragma unroll
        for (int j = 0; j < 4; ++j) acc[i][j] = (f32x4){0.f, 0.f, 0.f, 0.f};

#pragma unroll
    for (int kk = 0; kk < 2; ++kk) {
        const int k0 = kk * 32;
        bf16x8 ah[2], al[2];
#pragma unroll
        for (int nt = 0; nt < 2; ++nt) {
            const int n = w * 32 + nt * 16 + lr;
            ah[nt] = *(const bf16x8*)&BTs[0][SWZ64(n, k0 + lk)];
            al[nt] = *(const bf16x8*)&BTs[1][SWZ64(n, k0 + lk)];
        }
#pragma unroll
        for (int pt = 0; pt < 4; ++pt) {
            const int pr = pt * 16 + lr;
            const bf16x8 bh = *(const bf16x8*)&xwT[0][SWZ64(pr, k0 + lk)];
            const bf16x8 bl = *(const bf16x8*)&xwT[1][SWZ64(pr, k0 + lk)];
#pragma unroll
            for (int nt = 0; nt < 2; ++nt) {
                acc[nt][pt] = __builtin_amdgcn_mfma_f32_16x16x32_bf16(ah[nt], bh, acc[nt][pt], 0, 0, 0);
                acc[nt][pt] = __builtin_amdgcn_mfma_f32_16x16x32_bf16(ah[nt], bl, acc[nt][pt], 0, 0, 0);
                acc[nt][pt] = __builtin_amdgcn_mfma_f32_16x16x32_bf16(al[nt], bh, acc[nt][pt], 0, 0, 0);
            }
        }
    }

    const int crow = (lane >> 4) * 4;
#pragma unroll
    for (int nt = 0; nt < 2; ++nt)
#pragma unroll
        for (int pt = 0; pt < 4; ++pt)
#pragma unroll
            for (int r = 0; r < 4; ++r) {
                const int n = w * 32 + nt * 16 + crow + r;
                hloc[(size_t)bhc * 8192 + (size_t)n * 64 + pt * 16 + lr] = f2bfu(acc[nt][pt][r]);
            }
}

// ---------------------------------------------------------------------------
// combine: sequential over 32 chunks, bf16 storage, fp32 register recursion.
// ---------------------------------------------------------------------------
__global__ __launch_bounds__(256)
void combine_kernel(unsigned short* __restrict__ hloc,
                    const float* __restrict__ ptot)
{
    const int bid = blockIdx.x;
    const int bh = bid >> 3;
    const int chunk = bid & 7;
    const int e0 = chunk * 1024 + threadIdx.x * 4;

    float s0 = 0.f, s1 = 0.f, s2 = 0.f, s3 = 0.f;
    for (int k = 0; k < NSEG; ++k) {
        unsigned short* p = &hloc[((size_t)bh * NSEG + k) * 8192 + e0];
        const uint2 vp = *(const uint2*)p;
        const float v0 = bfu2f((unsigned short)(vp.x & 0xffff));
        const float v1 = bfu2f((unsigned short)(vp.x >> 16));
        const float v2 = bfu2f((unsigned short)(vp.y & 0xffff));
        const float v3 = bfu2f((unsigned short)(vp.y >> 16));
        uint2 op;
        op.x = (unsigned)f2bfu(s0) | ((unsigned)f2bfu(s1) << 16);
        op.y = (unsigned)f2bfu(s2) | ((unsigned)f2bfu(s3) << 16);
        *(uint2*)p = op;
        const float pt = ptot[bh * NSEG + k];
        s0 = fmaf(pt, s0, v0);
        s1 = fmaf(pt, s1, v1);
        s2 = fmaf(pt, s2, v2);
        s3 = fmaf(pt, s3, v3);
    }
}

// ---------------------------------------------------------------------------
// y: per (b,chunk,headgroup-of-4), 512 thr. Fuses D-skip; writes bf16 y.
// ---------------------------------------------------------------------------
__global__ __launch_bounds__(512)
void y_kernel(const unsigned short* __restrict__ Ch,
              const float* __restrict__ CBg,
              const float* __restrict__ lB,
              const float* __restrict__ dtb,
              const float* __restrict__ xh,
              const unsigned short* __restrict__ hloc,
              const float* __restrict__ dskip,
              unsigned short* __restrict__ ybh)
{
    __shared__ __align__(16) unsigned short CsA[64 * 128];     // C hi [t][n]
    __shared__ __align__(16) unsigned short opB[64 * 128];     // h0T / xT (bf16)
    __shared__ __align__(16) unsigned short Ms[64 * 64];       // M hi [t][s]
    __shared__ float ls4[256], dt4[256];

    const int gid = blockIdx.x;
    const int hg = gid & 3, bc = gid >> 2;
    const int chunk = bc & 31, b = bc >> 5;
    const size_t row0 = (size_t)b * SEQ + (size_t)chunk * TSEG;
    const int tid = threadIdx.x;

    const size_t cbase = (size_t)bc * 8192;
#pragma unroll
    for (int i = 0; i < 2; ++i) {
        const int bi = tid + i * 512;           // 16B block 0..1023
        const int r = bi >> 4, c = (bi & 15) << 3;
        *(uint4*)&CsA[SWZ128(r, c)] = ((const uint4*)(Ch + cbase))[bi];
    }
    if (tid < 256) {
        const int e = tid >> 6, t = tid & 63;
        const int h = hg * 4 + e;
        const int bhc = (b * NHEADS + h) * NSEG + chunk;
        ls4[tid] = lB[(size_t)bhc * 64 + t];
        dt4[tid] = dtb[(row0 + t) * NHEADS + h];
    }
    __syncthreads();

    const int w = tid >> 6, lane = tid & 63;
    const int lr = lane & 15, lk = (lane >> 4) * 8;
    const int tt = w & 3, ph = w >> 2;
    const int crow = (lane >> 4) * 4;
    const float* CBc = CBg + (size_t)bc * 4096;

    for (int e = 0; e < 4; ++e) {
        const int h = hg * 4 + e;
        const int bhc = (b * NHEADS + h) * NSEG + chunk;
        const unsigned short* h0p = hloc + (size_t)bhc * 8192;
        const float dsk = dskip[h];

        // transpose h0 (bf16) -> opB [p][n], direct from global (n-major src)
        {
            const int n = tid & 127;
            const int pb = (tid >> 7) * 16;
            const unsigned short* hr = &h0p[(size_t)n * 64 + pb];
#pragma unroll
            for (int i = 0; i < 16; ++i)
                opB[SWZ128(pb + i, n)] = hr[i];
        }
        __syncthreads();

        // MFMA phase A: acc = C @ h0 (K=128), hi x hi (1 pass)
        f32x4 acc[2];
        acc[0] = (f32x4){0.f, 0.f, 0.f, 0.f};
        acc[1] = (f32x4){0.f, 0.f, 0.f, 0.f};
#pragma unroll
        for (int kk = 0; kk < 4; ++kk) {
            const int k0 = kk * 32;
            const bf16x8 ah = *(const bf16x8*)&CsA[SWZ128(tt * 16 + lr, k0 + lk)];
#pragma unroll
            for (int pt = 0; pt < 2; ++pt) {
                const int pc = (ph * 2 + pt) * 16 + lr;
                const bf16x8 bh = *(const bf16x8*)&opB[SWZ128(pc, k0 + lk)];
                acc[pt] = __builtin_amdgcn_mfma_f32_16x16x32_bf16(ah, bh, acc[pt], 0, 0, 0);
            }
        }
        // row scale by exp(l[t])
        {
            float el[4];
#pragma unroll
            for (int r = 0; r < 4; ++r) el[r] = __expf(ls4[e * 64 + tt * 16 + crow + r]);
#pragma unroll
            for (int pt = 0; pt < 2; ++pt)
#pragma unroll
                for (int r = 0; r < 4; ++r) acc[pt][r] *= el[r];
        }
        __syncthreads();   // phase-A reads of opB done before overwrite

        // form M hi + transpose x -> opB [p][s], direct from global
#pragma unroll
        for (int i = 0; i < 8; ++i) {
            const int lin = tid * 8 + i;
            const int t = lin >> 6, s = lin & 63;
            float m = 0.0f;
            if (s <= t)
                m = CBc[t * 64 + s] * dt4[e * 64 + s] * __expf(ls4[e * 64 + t] - ls4[e * 64 + s]);
            Ms[SWZ64(t, s)] = f2bfu(m);
        }
        {
            const int s = tid & 63;
            const int pb = (tid >> 6) * 8;
            const float* xr = &xh[(row0 + s) * DINNER + h * HEADDIM + pb];
#pragma unroll
            for (int i = 0; i < 8; ++i) {
                const int p = pb + i;
                opB[SWZ64(p, s)] = f2bfu(xr[i]);
            }
        }
        __syncthreads();

        // MFMA phase B: acc += M @ x (K=64), hi x hi (1 pass)
#pragma unroll
        for (int kk = 0; kk < 2; ++kk) {
            const int k0 = kk * 32;
            const bf16x8 ah = *(const bf16x8*)&Ms[SWZ64(tt * 16 + lr, k0 + lk)];
#pragma unroll
            for (int pt = 0; pt < 2; ++pt) {
                const int pc = (ph * 2 + pt) * 16 + lr;
                const bf16x8 bh = *(const bf16x8*)&opB[SWZ64(pc, k0 + lk)];
                acc[pt] = __builtin_amdgcn_mfma_f32_16x16x32_bf16(ah, bh, acc[pt], 0, 0, 0);
            }
        }

        // write y (bf16) with fused D-skip
#pragma unroll
        for (int pt = 0; pt < 2; ++pt)
#pragma unroll
            for (int r = 0; r < 4; ++r) {
                const size_t row = row0 + tt * 16 + crow + r;
                const int col = h * HEADDIM + (ph * 2 + pt) * 16 + lr;
                const float v = acc[pt][r] + dsk * xh[row * DINNER + col];
                ybh[row * DINNER + col] = f2bfu(v);
            }
        __syncthreads();   // opB reads done before next head's overwrite
    }
}

// ---------------------------------------------------------------------------
// Gate + RMSNorm; reads bf16 y and bf16 z; writes ynorm as split-bf16 planes.
// ---------------------------------------------------------------------------
__global__ __launch_bounds__(256)
void gate_kernel(const unsigned short* __restrict__ ybh,
                 const unsigned short* __restrict__ zxh,
                 const float* __restrict__ nw,
                 unsigned short* __restrict__ yh,
                 unsigned short* __restrict__ yl)
{
    const int row = blockIdx.x;
    const int c4 = threadIdx.x * 4;

    const uint2 yv = *(const uint2*)&ybh[(size_t)row * DINNER + c4];
    float4 y;
    y.x = bfu2f((unsigned short)(yv.x & 0xffff));
    y.y = bfu2f((unsigned short)(yv.x >> 16));
    y.z = bfu2f((unsigned short)(yv.y & 0xffff));
    y.w = bfu2f((unsigned short)(yv.y >> 16));

    const uint2 zv = *(const uint2*)&zxh[(size_t)row * DINPROJ + c4];
    float4 z;
    z.x = bfu2f((unsigned short)(zv.x & 0xffff));
    z.y = bfu2f((unsigned short)(zv.x >> 16));
    z.z = bfu2f((unsigned short)(zv.y & 0xffff));
    z.w = bfu2f((unsigned short)(zv.y >> 16));

    float4 g;
    g.x = y.x * silu_f(z.x);
    g.y = y.y * silu_f(z.y);
    g.z = y.z * silu_f(z.z);
    g.w = y.w * silu_f(z.w);

    float local = g.x * g.x + g.y * g.y + g.z * g.z + g.w * g.w;
#pragma unroll
    for (int m = 32; m >= 1; m >>= 1) local += __shfl_xor(local, m, 64);

    __shared__ float red[4];
    if ((threadIdx.x & 63) == 0) red[threadIdx.x >> 6] = local;
    __syncthreads();
    const float total = red[0] + red[1] + red[2] + red[3];
    const float scale = rsqrtf(total * (1.0f / (float)DINNER) + 1e-5f);

    const float4 w = *(const float4*)&nw[c4];
    float o[4];
    o[0] = g.x * scale * w.x;
    o[1] = g.y * scale * w.y;
    o[2] = g.z * scale * w.z;
    o[3] = g.w * scale * w.w;

    unsigned hv[4], lv[4];
#pragma unroll
    for (int j = 0; j < 4; ++j) {
        hv[j] = f2bfu(o[j]);
        lv[j] = f2bfu(o[j] - bfu2f((unsigned short)hv[j]));
    }
    const size_t oi = (size_t)row * DINNER + c4;
    *(uint2*)&yh[oi] = make_uint2(hv[0] | (hv[1] << 16), hv[2] | (hv[3] << 16));
    *(uint2*)&yl[oi] = make_uint2(lv[0] | (lv[1] << 16), lv[2] | (lv[3] << 16));
}

// ---------------------------------------------------------------------------
extern "C" void kernel_launch(void* const* d_in, const int* in_sizes, int n_in,
                              void* d_out, int out_size, void* d_ws, size_t ws_size,
                              hipStream_t stream)
{
    const float* x_in    = (const float*)d_in[0];
    const float* in_w    = (const float*)d_in[1];
    const float* conv_w  = (const float*)d_in[2];
    const float* conv_b  = (const float*)d_in[3];
    const float* dt_bias = (const float*)d_in[4];
    const float* A_log   = (const float*)d_in[5];
    const float* D_skip  = (const float*)d_in[6];
    const float* norm_w  = (const float*)d_in[7];
    const float* out_w   = (const float*)d_in[8];
    float* out = (float*)d_out;

    float* ws   = (float*)d_ws;
    float* zx   = ws;                               // region 19,005,440 f (zx bf16 + dtraw)
    float* xh   = zx   + (size_t)ROWS * DINPROJ;    //  8,388,608 f
    float* Bb   = xh   + (size_t)ROWS * DINNER;     //  1,048,576 f (unused)
    float* Cb   = Bb   + (size_t)ROWS * DSTATE;     //  1,048,576 f (unused)
    float* dtb  = Cb   + (size_t)ROWS * DSTATE;     //    131,072 f
    float* dAb  = dtb  + (size_t)ROWS * NHEADS;     //    131,072 f
    float* yb   = dAb  + (size_t)ROWS * NHEADS;     //  8,388,608 f (bf16 y lives here)
    float* UN   = yb   + (size_t)ROWS * DINNER;     // 16,777,216 f (union)
    float* BtF  = UN   + (size_t)16777216;          //  1,245,184 f
    float* WtF  = BtF  + (size_t)1245184;           //    524,288 f
    float* ptot = WtF  + (size_t)524288;            //      2,048 f
    float* lB   = ptot + (size_t)2048;              //    131,072 f
    float* wB   = lB   + (size_t)131072;            //    131,072 f
    float* BTf  = wB   + (size_t)131072;            //  1,048,576 f
    float* Bspf = BTf  + (size_t)1048576;           //  1,048,576 f
    float* Cspf = Bspf + (size_t)1048576;           //  1,048,576 f
    float* CBb  = Cspf + (size_t)1048576;           //    524,288 f
    // total 60,622,848 f = 242.5 MB

    unsigned short* zxh = (unsigned short*)zx;                // bf16 [8192][2320]
    float* dtraw = zx + 10485760;                             // fp32 [8192][16]
    unsigned short* ybh = (unsigned short*)yb;                // bf16 y [8192][1024]
    unsigned short* hloc_us = (unsigned short*)UN;            // [0 .. 8.39M)
    unsigned short* yh = (unsigned short*)UN;                 // [0 .. 8.39M)
    unsigned short* yl = yh + (size_t)ROWS * DINNER;          // [8.39M .. 16.78M)
    unsigned short* Ah = (unsigned short*)UN + 16777216;      // [16.78M .. 20.97M)
    unsigned short* Al = Ah + (size_t)ROWS * DMODEL;          // [20.97M .. 25.17M)

    unsigned short* Bth = (unsigned short*)BtF;               // [2432][512]
    unsigned short* Btl = Bth + (size_t)NPAD_IN * DMODEL;
    unsigned short* Wth = (unsigned short*)WtF;               // [512][1024]
    unsigned short* Wtl = Wth + (size_t)DMODEL * DINNER;

    unsigned short* BTh = (unsigned short*)BTf;               // [128][128][64]
    unsigned short* BTl = BTh + (size_t)128 * 8192;
    unsigned short* Bsph = (unsigned short*)Bspf;             // [8192][128]
    unsigned short* Bspl = Bsph + (size_t)ROWS * DSTATE;
    unsigned short* Csph = (unsigned short*)Cspf;             // [8192][128]
    unsigned short* Cspl = Csph + (size_t)ROWS * DSTATE;

    for (int layer = 0; layer < 2; ++layer) {
        if (layer == 0)
            split_a_kernel<<<(ROWS * DMODEL) / (256 * 8), 256, 0, stream>>>(x_in, Ah, Al);
        // layer 1: Ah/Al already written by layer-0 out-proj epilogue

        tsplit_w_kernel<<<dim3(NPAD_IN / 32, DMODEL / 32), 256, 0, stream>>>(
            in_w + (size_t)layer * DMODEL * DINPROJ, DMODEL, DINPROJ, Bth, Btl);

        gemm_bf16s<<<dim3(NPAD_IN / 128, ROWS / 128), 256, 0, stream>>>(
            Ah, Al, Bth, Btl, nullptr, zxh, DINPROJ, DINPROJ, DMODEL,
            DINNER + CONVDIM, dtraw, nullptr, nullptr);

        conv_kernel<<<ROWS, CONVDIM / 4, 0, stream>>>(
            zxh, dtraw,
            conv_w + (size_t)layer * DCONV * CONVDIM,
            conv_b + (size_t)layer * CONVDIM,
            dt_bias + (size_t)layer * NHEADS,
            A_log + (size_t)layer * NHEADS,
            xh, Bsph, Bspl, Csph, Cspl, dtb, dAb);

        meta_kernel<<<BATCH * NHEADS * NSEG, 64, 0, stream>>>(
            dtb, A_log + (size_t)layer * NHEADS, lB, wB, ptot);

        tsplit_bf16_kernel<<<BATCH * NSEG * 2, 256, 0, stream>>>(
            Bsph, Bspl, BTh, BTl);

        cb_kernel<<<BATCH * NSEG, 256, 0, stream>>>(Csph, Cspl, Bsph, Bspl, CBb);

        state_kernel<<<BATCH * NHEADS * NSEG, 256, 0, stream>>>(
            BTh, BTl, xh, wB, hloc_us);

        combine_kernel<<<BATCH * NHEADS * 8, 256, 0, stream>>>(hloc_us, ptot);

        y_kernel<<<BATCH * NSEG * 4, 512, 0, stream>>>(
            Csph, CBb, lB, dtb, xh, hloc_us,
            D_skip + (size_t)layer * NHEADS, ybh);

        gate_kernel<<<ROWS, 256, 0, stream>>>(
            ybh, zxh, norm_w + (size_t)layer * DINNER, yh, yl);

        tsplit_w_kernel<<<dim3(DMODEL / 32, DINNER / 32), 256, 0, stream>>>(
            out_w + (size_t)layer * DINNER * DMODEL, DINNER, DMODEL, Wth, Wtl);

        // out-proj: 128x64-tile kernel (grid 8x64 = 512 blocks)
        gemm_bf16s_n64<<<dim3(DMODEL / 64, ROWS / 128), 256, 0, stream>>>(
            yh, yl, Wth, out, DMODEL, DMODEL, DINNER,
            (layer == 0) ? Ah : nullptr,
            (layer == 0) ? Al : nullptr);
    }
}